// Round 13
// baseline (1258.893 us; speedup 1.0000x reference)
//
#include <hip/hip_runtime.h>
#include <hip/hip_bf16.h>
#include <math.h>

// Problem dims
#define BB 8
#define TT 16
#define HH 112
#define WW 112
#define CC 3
#define FF 16
#define HP 56
#define WP 56
#define HO 54
#define WO 54
#define NC 6

#define NPIX (BB*HO*WO)               // 23328
#define SPIX (HO*WO)                  // 2916
#define NPT  (BB*TT*SPIX)             // 373248  (b,t,pixel)

// ws layout (float offsets)
#define POOLED_ELEMS (128*56*56*16)   // 6,422,528
#define HSTATE_ELEMS (BB*SPIX*16)     // 373,248
#define WPACK_ELEMS  9216             // wrq [4 cq][9 tap][16 ci][4 c4][4 g]

typedef __attribute__((ext_vector_type(2))) float f2;

__device__ __forceinline__ float hsig(float x) {
    return fminf(fmaxf(0.2f*x + 0.5f, 0.0f), 1.0f);
}
__device__ __forceinline__ f2 f2max(f2 a, f2 b) {
    f2 r; r.x = fmaxf(a.x, b.x); r.y = fmaxf(a.y, b.y); return r;
}

// Kernel 0: repack wr into [cq4][tap][ci][c4][g] — per (tap,ci) a contiguous
// 16-float block (4 ch x 4 gates) for the wave-uniform channel-quad consumer.
__global__ __launch_bounds__(256) void repack_kernel(
    const float* __restrict__ wr, float* __restrict__ wrq)
{
    int j = blockIdx.x * 256 + threadIdx.x;        // 36*256 = 9216 exact
    int g   = j & 3;
    int c4  = (j >> 2) & 3;
    int ci  = (j >> 4) & 15;
    int tap = (j >> 8) % 9;
    int cq  = (j >> 8) / 9;
    wrq[j] = wr[tap*1024 + ci*64 + g*16 + cq*4 + c4];
}

// Kernel 1: fused 7x7 SAME conv (3->16) + bias + relu + 2x2 maxpool.
// (unchanged from R11: parity-plane LDS tile, residual 2-way conflicts benign)
__global__ __launch_bounds__(256, 4) void conv_pool_kernel(
    const float* __restrict__ x,      // [128,112,112,3]
    const float* __restrict__ cw,     // [7,7,3,16]
    const float* __restrict__ cb,     // [16]
    float* __restrict__ pooled)       // [128,56,56,16]
{
    int fr = blockIdx.y;
    int tx = blockIdx.x & 1, ty = blockIdx.x >> 1;   // 2 x 7 tiles
    int col0 = tx*28, row0 = ty*8;
    int tid = threadIdx.x;
    const float* xf = x + (size_t)fr * (HH*WW*CC);

    __shared__ float xs[2*22*31*3];
    {
        int ir0 = 2*row0 - 3;
        int ic0 = 2*col0 - 3;
        #pragma unroll 1
        for (int i = tid; i < 22*62*3; i += 256) {
            int iy  = i / 186;
            int rem = i - iy*186;
            int c   = rem / 3;
            int ci  = rem - c*3;
            int gr = ir0 + iy;
            int gc = ic0 + c;
            bool ok = (gr >= 0) & (gr < HH) & (gc >= 0) & (gc < WW);
            float v = ok ? xf[(gr*WW + gc)*3 + ci] : 0.f;
            xs[(c & 1)*2046 + iy*93 + (c >> 1)*3 + ci] = v;
        }
    }
    __syncthreads();

    if (tid >= 224) return;
    int lx = tid % 28, ly = tid / 28;

    const f2* cb2 = (const f2*)cb;
    f2 best[8];
    #pragma unroll
    for (int i = 0; i < 8; ++i) { best[i].x = -1e30f; best[i].y = -1e30f; }

    #pragma unroll 1
    for (int pos = 0; pos < 4; ++pos) {
        int py = pos >> 1, px = pos & 1;
        f2 acc[8];
        #pragma unroll
        for (int i = 0; i < 8; ++i) acc[i] = cb2[i];
        #pragma unroll 1
        for (int ky = 0; ky < 7; ++ky) {
            int row = 2*ly + py + ky;
            const float* rowbase = &xs[row*93 + lx*3];
            #pragma unroll 1
            for (int kx = 0; kx < 7; ++kx) {
                int s = px + kx;
                const float* xp = rowbase + (s & 1)*2046 + (s >> 1)*3;
                const f2* wv = (const f2*)(cw + ((ky*7 + kx)*3)*16);
                #pragma unroll
                for (int ci = 0; ci < 3; ++ci) {
                    float a = xp[ci];
                    #pragma unroll
                    for (int i8 = 0; i8 < 8; ++i8)
                        acc[i8] += a * wv[ci*8 + i8];
                }
            }
        }
        #pragma unroll
        for (int i = 0; i < 8; ++i) best[i] = f2max(best[i], acc[i]);
    }

    int pr = row0 + ly, pc = col0 + lx;
    float4* op = (float4*)(pooled + (((size_t)fr*HP + pr)*WP + pc)*16);
    #pragma unroll
    for (int v = 0; v < 4; ++v) {
        float4 o;
        o.x = fmaxf(best[v*2+0].x, 0.0f);
        o.y = fmaxf(best[v*2+0].y, 0.0f);
        o.z = fmaxf(best[v*2+1].x, 0.0f);
        o.w = fmaxf(best[v*2+1].y, 0.0f);
        op[v] = o;
    }
}

// Kernel 2a: precompute zx for ALL t (unchanged from R11: 2-way gate split).
__global__ __launch_bounds__(256, 4) void zx_all_kernel(
    const float* __restrict__ pooled,   // [128,56,56,16]
    const float* __restrict__ wk,       // [3,3,16,64] original
    __hip_bfloat16* __restrict__ zx)    // [64][373248]
{
    int gh = blockIdx.y;                // 0..1, gate planes gh*32 .. gh*32+31
    int pt = blockIdx.x * 256 + threadIdx.x;   // 373248 exact
    int b  = pt / (TT*SPIX);
    int rt = pt % (TT*SPIX);
    int tt = rt / SPIX;
    int r  = rt % SPIX;
    int oh = r / WO, ow = r % WO;

    const float* pf = pooled + (size_t)(b*TT + tt) * HP * WP * 16;

    f2 acc[16];
    #pragma unroll
    for (int i = 0; i < 16; ++i) { acc[i].x = 0.f; acc[i].y = 0.f; }

    #pragma unroll 1
    for (int tap = 0; tap < 9; ++tap) {
        int ky = tap / 3;
        int kx = tap - ky * 3;
        const float4* pp = (const float4*)(pf + ((size_t)(oh+ky) * WP + (ow+kx)) * 16);
        float a[16];
        #pragma unroll
        for (int v = 0; v < 4; ++v) {
            float4 x4 = pp[v];
            a[v*4+0] = x4.x; a[v*4+1] = x4.y; a[v*4+2] = x4.z; a[v*4+3] = x4.w;
        }
        const float* wt = wk + tap * 1024 + gh * 32;
        #pragma unroll 1
        for (int ci = 0; ci < 16; ++ci) {
            float av = a[ci];
            const f2* wv = (const f2*)(wt + ci * 64);
            #pragma unroll
            for (int g = 0; g < 16; ++g)
                acc[g] += av * wv[g];
        }
    }

    #pragma unroll
    for (int g = 0; g < 16; ++g) {
        zx[(size_t)(gh*32 + 2*g + 0) * NPT + pt] = __float2bfloat16(acc[g].x);
        zx[(size_t)(gh*32 + 2*g + 1) * NPT + pt] = __float2bfloat16(acc[g].y);
    }
}

// Kernel 2b: TWO ConvLSTM steps per launch via halo recomputation (temporal
// tiling) — no inter-block sync needed: blocks only read prev-launch buffers.
// Block = 8x8 interior tile x all 16 channels; wave w = channel quad (wave-
// uniform -> scalar weights). Step A computes h(t0),c(t0) on the 10x10
// extended region (ring redundantly recomputed, it's a neighbor's interior),
// staged through LDS; step B computes the 8x8 interior for t0+1 and writes
// h,c to global double-buffers. Halves the launch count (the ~11 us/launch
// overhead dominated R11's step budget; R8 showed grid barriers cost more).
__global__ __launch_bounds__(256, 4) void pair_step_kernel(
    const __hip_bfloat16* __restrict__ zx,  // [64][373248]
    const float* __restrict__ h_in,         // state h(t0-1)
    float* __restrict__ h_out,              // state h(t0+1)
    const float* __restrict__ c_in,         // state c(t0-1)
    float* __restrict__ c_out,              // state c(t0+1)
    const float* __restrict__ wrq,          // [cq][tap][ci][c4][g]
    const float* __restrict__ bias,         // [64]
    int t0)
{
    int bid = blockIdx.x;               // 0..48
    int tx = bid % 7, ty = bid / 7;
    int b  = blockIdx.y;
    int x0 = tx*8, y0 = ty*8;
    int tid = threadIdx.x;
    int lane = tid & 63;
    int cq = tid >> 6;                  // wave-uniform channel quad
    const float* wq = wrq + cq * 2304;  // 9*16*16

    const float* hgb = h_in + (size_t)b * SPIX * 16;
    const float* cgb = c_in + (size_t)b * SPIX * 16;

    __shared__ float4 hA_lds[4][144];   // h(t0-1), region 12x12, quad-planar
    __shared__ float4 hB_lds[4][100];   // h(t0),   region 10x10
    __shared__ float4 c_lds[4][100];    // c(t0),   region 10x10, [cq][px]

    // Stage h(t0-1) on R2 = [y0-2..y0+9] x [x0-2..x0+9].
    if (tid < 144) {
        int iy = tid / 12, ix = tid % 12;
        int gy = y0 - 2 + iy, gx = x0 - 2 + ix;
        bool ok = (gy >= 0) & (gy < HO) & (gx >= 0) & (gx < WO);
        const float4* src = (const float4*)(hgb + ((size_t)gy * WO + gx) * 16);
        #pragma unroll
        for (int v = 0; v < 4; ++v)
            hA_lds[v][tid] = ok ? src[v] : make_float4(0.f,0.f,0.f,0.f);
    }
    __syncthreads();

    float bi[4], bf[4], bg[4], bo[4];
    #pragma unroll
    for (int c4 = 0; c4 < 4; ++c4) {
        int ch = cq*4 + c4;
        bi[c4] = bias[ 0 + ch]; bf[c4] = bias[16 + ch];
        bg[c4] = bias[32 + ch]; bo[c4] = bias[48 + ch];
    }

    size_t ptb = (size_t)b * (TT*SPIX);

    // ---- Phase 1: step A (t0) on R1 = 10x10 (2 rounds of 64 lanes) ----
    #pragma unroll 1
    for (int rnd = 0; rnd < 2; ++rnd) {
        int p = lane + rnd*64;
        bool act = p < 100;
        int py = p / 10, pxx = p % 10;
        int gy = y0 - 1 + py, gx = x0 - 1 + pxx;
        bool inimg = act & (gy >= 0) & (gy < HO) & (gx >= 0) & (gx < WO);

        float4 hn = make_float4(0.f,0.f,0.f,0.f);
        float4 cn = make_float4(0.f,0.f,0.f,0.f);
        if (inimg) {
            int rpix = gy * WO + gx;
            size_t pt = ptb + (size_t)t0 * SPIX + rpix;
            float z[16];                // [c4][g]
            #pragma unroll
            for (int g = 0; g < 4; ++g)
                #pragma unroll
                for (int c4 = 0; c4 < 4; ++c4)
                    z[c4*4 + g] = __bfloat162float(zx[(size_t)(g*16 + cq*4 + c4) * NPT + pt]);

            f2 acc[8];                  // acc[c4*2+0]=(gi,gf), [c4*2+1]=(gg,go)
            #pragma unroll
            for (int i = 0; i < 8; ++i) { acc[i].x = 0.f; acc[i].y = 0.f; }

            #pragma unroll 1
            for (int tap = 0; tap < 9; ++tap) {
                int ky = tap / 3, kx = tap - ky*3;
                int q = (py + ky)*12 + (pxx + kx);
                float h[16];
                #pragma unroll
                for (int v = 0; v < 4; ++v) {
                    float4 t4 = hA_lds[v][q];
                    h[v*4+0]=t4.x; h[v*4+1]=t4.y; h[v*4+2]=t4.z; h[v*4+3]=t4.w;
                }
                const float* wt = wq + tap * 256;
                #pragma unroll 1
                for (int qc = 0; qc < 4; ++qc) {    // 64 scalar floats live
                    const f2* wv = (const f2*)(wt + qc * 64);
                    #pragma unroll
                    for (int u = 0; u < 4; ++u) {
                        float hv = h[qc*4 + u];
                        #pragma unroll
                        for (int k = 0; k < 8; ++k)
                            acc[k] += hv * wv[u*8 + k];
                    }
                }
            }

            float4 cold = *(const float4*)(cgb + (size_t)rpix*16 + cq*4);
            float* co = &cold.x; float* cnp = &cn.x; float* hnp = &hn.x;
            #pragma unroll
            for (int c4 = 0; c4 < 4; ++c4) {
                float iv = hsig (z[c4*4+0] + acc[c4*2+0].x + bi[c4]);
                float fv = hsig (z[c4*4+1] + acc[c4*2+0].y + bf[c4]);
                float gv = tanhf(z[c4*4+2] + acc[c4*2+1].x + bg[c4]);
                float ov = hsig (z[c4*4+3] + acc[c4*2+1].y + bo[c4]);
                float cc = fv * co[c4] + iv * gv;
                cnp[c4] = cc;
                hnp[c4] = ov * tanhf(cc);
            }
        }
        if (act) {
            hB_lds[cq][p] = hn;         // zeros for out-of-image ring px
            c_lds[cq][p]  = cn;
        }
    }
    __syncthreads();

    // ---- Phase 2: step B (t0+1) on the 8x8 interior ----
    int ry = lane / 8, rx = lane % 8;
    int gy = y0 + ry, gx = x0 + rx;
    if ((gy < HO) & (gx < WO)) {
        int rpix = gy * WO + gx;
        size_t pt = ptb + (size_t)(t0+1) * SPIX + rpix;
        float z[16];
        #pragma unroll
        for (int g = 0; g < 4; ++g)
            #pragma unroll
            for (int c4 = 0; c4 < 4; ++c4)
                z[c4*4 + g] = __bfloat162float(zx[(size_t)(g*16 + cq*4 + c4) * NPT + pt]);

        f2 acc[8];
        #pragma unroll
        for (int i = 0; i < 8; ++i) { acc[i].x = 0.f; acc[i].y = 0.f; }

        #pragma unroll 1
        for (int tap = 0; tap < 9; ++tap) {
            int ky = tap / 3, kx = tap - ky*3;
            int q = (ry + ky)*10 + (rx + kx);
            float h[16];
            #pragma unroll
            for (int v = 0; v < 4; ++v) {
                float4 t4 = hB_lds[v][q];
                h[v*4+0]=t4.x; h[v*4+1]=t4.y; h[v*4+2]=t4.z; h[v*4+3]=t4.w;
            }
            const float* wt = wq + tap * 256;
            #pragma unroll 1
            for (int qc = 0; qc < 4; ++qc) {
                const f2* wv = (const f2*)(wt + qc * 64);
                #pragma unroll
                for (int u = 0; u < 4; ++u) {
                    float hv = h[qc*4 + u];
                    #pragma unroll
                    for (int k = 0; k < 8; ++k)
                        acc[k] += hv * wv[u*8 + k];
                }
            }
        }

        float4 cold = c_lds[cq][(ry+1)*10 + (rx+1)];
        float4 cn, hn;
        float* co = &cold.x; float* cnp = &cn.x; float* hnp = &hn.x;
        #pragma unroll
        for (int c4 = 0; c4 < 4; ++c4) {
            float iv = hsig (z[c4*4+0] + acc[c4*2+0].x + bi[c4]);
            float fv = hsig (z[c4*4+1] + acc[c4*2+0].y + bf[c4]);
            float gv = tanhf(z[c4*4+2] + acc[c4*2+1].x + bg[c4]);
            float ov = hsig (z[c4*4+3] + acc[c4*2+1].y + bo[c4]);
            float cc = fv * co[c4] + iv * gv;
            cnp[c4] = cc;
            hnp[c4] = ov * tanhf(cc);
        }
        size_t base = ((size_t)(b * SPIX + rpix)) * 16 + cq*4;
        *(float4*)&h_out[base] = hn;
        *(float4*)&c_out[base] = cn;
    }
}

// Kernel 3: spatial mean over 54x54 -> dense(16->6) -> softmax. One block per b.
__global__ __launch_bounds__(256) void head_kernel(
    const float* __restrict__ h,    // [8,54,54,16]
    const float* __restrict__ dw,   // [16,6]
    const float* __restrict__ db,   // [6]
    float* __restrict__ out)        // [8,6]
{
    int b = blockIdx.x;
    int tid = threadIdx.x;
    const float* hb = h + (size_t)b * SPIX * 16;
    float s = 0.0f;
    for (int i = tid; i < SPIX*16; i += 256) s += hb[i];
    __shared__ float red[256];
    red[tid] = s;
    __syncthreads();
    for (int st = 128; st >= 16; st >>= 1) {
        if (tid < st) red[tid] += red[tid + st];
        __syncthreads();
    }
    __shared__ float logits[8];
    if (tid < NC) {
        float l = db[tid];
        #pragma unroll
        for (int ch = 0; ch < 16; ++ch)
            l += (red[ch] * (1.0f/2916.0f)) * dw[ch*NC + tid];
        logits[tid] = l;
    }
    __syncthreads();
    if (tid < NC) {
        float m = -1e30f;
        for (int k = 0; k < NC; ++k) m = fmaxf(m, logits[k]);
        float e = expf(logits[tid] - m);
        float d = 0.0f;
        for (int k = 0; k < NC; ++k) d += expf(logits[k] - m);
        out[b*NC + tid] = e / d;
    }
}

extern "C" void kernel_launch(void* const* d_in, const int* in_sizes, int n_in,
                              void* d_out, int out_size, void* d_ws, size_t ws_size,
                              hipStream_t stream) {
    const float* x      = (const float*)d_in[0];
    const float* conv_w = (const float*)d_in[1];
    const float* conv_b = (const float*)d_in[2];
    const float* wk     = (const float*)d_in[3];
    const float* wr     = (const float*)d_in[4];
    const float* bias   = (const float*)d_in[5];
    const float* dw     = (const float*)d_in[6];
    const float* db     = (const float*)d_in[7];
    float* out = (float*)d_out;

    float* ws     = (float*)d_ws;
    float* pooled = ws;                                   // 6,422,528 f
    float* hA     = pooled + POOLED_ELEMS;                //   373,248 f
    float* hB     = hA + HSTATE_ELEMS;
    float* cA     = hB + HSTATE_ELEMS;
    float* cB     = cA + HSTATE_ELEMS;
    float* wrq    = cB + HSTATE_ELEMS;                    //     9,216 f
    __hip_bfloat16* zx = (__hip_bfloat16*)(wrq + WPACK_ELEMS); // 47.8 MB

    // h(-1) = 0, c(-1) = 0 (ws is poisoned before every launch)
    hipMemsetAsync(hA, 0, HSTATE_ELEMS * sizeof(float), stream);
    hipMemsetAsync(cA, 0, HSTATE_ELEMS * sizeof(float), stream);

    repack_kernel<<<dim3(36), dim3(256), 0, stream>>>(wr, wrq);
    conv_pool_kernel<<<dim3(14, 128), dim3(256), 0, stream>>>(x, conv_w, conv_b, pooled);
    zx_all_kernel<<<dim3(1458, 2), dim3(256), 0, stream>>>(pooled, wk, zx);

    // 8 pair launches: j reads state (2j-1), writes state (2j+1).
    for (int j = 0; j < 8; ++j) {
        const float* hin  = (j & 1) ? hB : hA;
        float*       hout = (j & 1) ? hA : hB;
        const float* cin  = (j & 1) ? cB : cA;
        float*       cout = (j & 1) ? cA : cB;
        pair_step_kernel<<<dim3(49, 8), dim3(256), 0, stream>>>(
            zx, hin, hout, cin, cout, wrq, bias, 2*j);
    }
    // j=7 wrote hA
    head_kernel<<<dim3(8), dim3(256), 0, stream>>>(hA, dw, db, out);
}

// Round 14
// 459.295 us; speedup vs baseline: 2.7409x; 2.7409x over previous
//
#include <hip/hip_runtime.h>
#include <hip/hip_bf16.h>
#include <math.h>

// Problem dims
#define BB 8
#define TT 16
#define HH 112
#define WW 112
#define CC 3
#define FF 16
#define HP 56
#define WP 56
#define HO 54
#define WO 54
#define NC 6

#define NPIX (BB*HO*WO)               // 23328
#define SPIX (HO*WO)                  // 2916
#define NPT  (BB*TT*SPIX)             // 373248  (b,t,pixel)

// ws layout (float offsets)
#define POOLED_ELEMS (128*56*56*16)   // 6,422,528
#define HSTATE_ELEMS (BB*SPIX*16)     // 373,248
#define WPACK_ELEMS  9216             // wrpack [8 cg][9 tap][16 ci][2 c][4 g]

typedef __attribute__((ext_vector_type(2))) float f2;

__device__ __forceinline__ float hsig(float x) {
    return fminf(fmaxf(0.2f*x + 0.5f, 0.0f), 1.0f);
}
__device__ __forceinline__ f2 f2max(f2 a, f2 b) {
    f2 r; r.x = fmaxf(a.x, b.x); r.y = fmaxf(a.y, b.y); return r;
}

// Kernel 0: repack wr into [cg8][tap][ci][c2][g] (step-kernel consumer layout).
__global__ __launch_bounds__(256) void repack_kernel(
    const float* __restrict__ wr, float* __restrict__ wpack)
{
    int j = blockIdx.x * 256 + threadIdx.x;        // 36*256 = 9216 exact
    int g   = j & 3;
    int c   = (j >> 2) & 1;
    int ci  = (j >> 3) & 15;
    int tap = (j >> 7) % 9;
    int cg8 = (j >> 7) / 9;
    wpack[j] = wr[tap*1024 + ci*64 + g*16 + cg8*2 + c];
}

// Kernel 1: fused 7x7 SAME conv (3->16) + bias + relu + 2x2 maxpool.
// Parity-plane LDS tile (R11). kx now FULLY UNROLLED: s=px+kx parity offsets
// become compile-time per instance, killing the per-iter address math + branch
// that held VALU at 67% busy with only 2/3 of issue being FMAs.
__global__ __launch_bounds__(256, 4) void conv_pool_kernel(
    const float* __restrict__ x,      // [128,112,112,3]
    const float* __restrict__ cw,     // [7,7,3,16]
    const float* __restrict__ cb,     // [16]
    float* __restrict__ pooled)       // [128,56,56,16]
{
    int fr = blockIdx.y;
    int tx = blockIdx.x & 1, ty = blockIdx.x >> 1;   // 2 x 7 tiles
    int col0 = tx*28, row0 = ty*8;
    int tid = threadIdx.x;
    const float* xf = x + (size_t)fr * (HH*WW*CC);

    __shared__ float xs[2*22*31*3];
    {
        int ir0 = 2*row0 - 3;
        int ic0 = 2*col0 - 3;
        #pragma unroll 1
        for (int i = tid; i < 22*62*3; i += 256) {
            int iy  = i / 186;
            int rem = i - iy*186;
            int c   = rem / 3;
            int ci  = rem - c*3;
            int gr = ir0 + iy;
            int gc = ic0 + c;
            bool ok = (gr >= 0) & (gr < HH) & (gc >= 0) & (gc < WW);
            float v = ok ? xf[(gr*WW + gc)*3 + ci] : 0.f;
            xs[(c & 1)*2046 + iy*93 + (c >> 1)*3 + ci] = v;
        }
    }
    __syncthreads();

    if (tid >= 224) return;
    int lx = tid % 28, ly = tid / 28;

    const f2* cb2 = (const f2*)cb;
    f2 best[8];
    #pragma unroll
    for (int i = 0; i < 8; ++i) { best[i].x = -1e30f; best[i].y = -1e30f; }

    #pragma unroll 1
    for (int pos = 0; pos < 4; ++pos) {
        int py = pos >> 1, px = pos & 1;
        f2 acc[8];
        #pragma unroll
        for (int i = 0; i < 8; ++i) acc[i] = cb2[i];
        #pragma unroll 1
        for (int ky = 0; ky < 7; ++ky) {
            int row = 2*ly + py + ky;
            const float* rowbase = &xs[row*93 + lx*3];
            #pragma unroll
            for (int kx = 0; kx < 7; ++kx) {
                int s = px + kx;                // px runtime 0/1, kx const
                const float* xp = rowbase + (s & 1)*2046 + (s >> 1)*3;
                const f2* wv = (const f2*)(cw + ((ky*7 + kx)*3)*16);
                #pragma unroll
                for (int ci = 0; ci < 3; ++ci) {
                    float a = xp[ci];
                    #pragma unroll
                    for (int i8 = 0; i8 < 8; ++i8)
                        acc[i8] += a * wv[ci*8 + i8];
                }
            }
        }
        #pragma unroll
        for (int i = 0; i < 8; ++i) best[i] = f2max(best[i], acc[i]);
    }

    int pr = row0 + ly, pc = col0 + lx;
    float4* op = (float4*)(pooled + (((size_t)fr*HP + pr)*WP + pc)*16);
    #pragma unroll
    for (int v = 0; v < 4; ++v) {
        float4 o;
        o.x = fmaxf(best[v*2+0].x, 0.0f);
        o.y = fmaxf(best[v*2+0].y, 0.0f);
        o.z = fmaxf(best[v*2+1].x, 0.0f);
        o.w = fmaxf(best[v*2+1].y, 0.0f);
        op[v] = o;
    }
}

// Kernel 2a: precompute zx = conv3x3 VALID (pooled -> 64 gates) for ALL t.
// 2-way gate split (R11). ci loop unrolled x2: two 32-float scalar-weight
// batches in flight pipelines the s_load waits that held VALUBusy at 45%.
__global__ __launch_bounds__(256, 4) void zx_all_kernel(
    const float* __restrict__ pooled,   // [128,56,56,16]
    const float* __restrict__ wk,       // [3,3,16,64] original
    __hip_bfloat16* __restrict__ zx)    // [64][373248]
{
    int gh = blockIdx.y;                // 0..1, gate planes gh*32 .. gh*32+31
    int pt = blockIdx.x * 256 + threadIdx.x;   // 373248 exact
    int b  = pt / (TT*SPIX);
    int rt = pt % (TT*SPIX);
    int tt = rt / SPIX;
    int r  = rt % SPIX;
    int oh = r / WO, ow = r % WO;

    const float* pf = pooled + (size_t)(b*TT + tt) * HP * WP * 16;

    f2 acc[16];
    #pragma unroll
    for (int i = 0; i < 16; ++i) { acc[i].x = 0.f; acc[i].y = 0.f; }

    #pragma unroll 1
    for (int tap = 0; tap < 9; ++tap) {
        int ky = tap / 3;
        int kx = tap - ky * 3;
        const float4* pp = (const float4*)(pf + ((size_t)(oh+ky) * WP + (ow+kx)) * 16);
        float a[16];
        #pragma unroll
        for (int v = 0; v < 4; ++v) {
            float4 x4 = pp[v];
            a[v*4+0] = x4.x; a[v*4+1] = x4.y; a[v*4+2] = x4.z; a[v*4+3] = x4.w;
        }
        const float* wt = wk + tap * 1024 + gh * 32;
        #pragma unroll 2
        for (int ci = 0; ci < 16; ++ci) {       // x2: 64 scalar floats in flight
            float av = a[ci];
            const f2* wv = (const f2*)(wt + ci * 64);
            #pragma unroll
            for (int g = 0; g < 16; ++g)
                acc[g] += av * wv[g];
        }
    }

    #pragma unroll
    for (int g = 0; g < 16; ++g) {
        zx[(size_t)(gh*32 + 2*g + 0) * NPT + pt] = __float2bfloat16(acc[g].x);
        zx[(size_t)(gh*32 + 2*g + 1) * NPT + pt] = __float2bfloat16(acc[g].y);
    }
}

// Kernel 2b: one ConvLSTM step (R11 exactly: planar LDS h-tile, conflict-free
// b128, 8-way cg split -> 3072 waves, scalar wr weights). R12's 2-step fusion
// regressed 7x: wave count fell 2x, per-wave scalar stream doubled -> 90%
// stall at 1.5 waves/SIMD. Wall time ~ serial-latency/waves-per-SIMD.
__global__ __launch_bounds__(256, 4) void lstm_step_kernel(
    const __hip_bfloat16* __restrict__ zx,  // [64][373248]
    const float* __restrict__ h_in,         // [8,54,54,16]
    float* __restrict__ h_out,
    float* __restrict__ cst,
    const float* __restrict__ wrpack,       // [cg8][tap][ci][c2][g]
    const float* __restrict__ bias,         // [64]
    int t)
{
    int tileid = blockIdx.x;      // 0..11
    int tx = tileid % 3;
    int ty = tileid / 3;
    int b  = blockIdx.y;
    int cg = blockIdx.z;          // 0..7, channels cg*2, cg*2+1
    const float* wcg = wrpack + cg * 1152;

    int tid = threadIdx.x;
    int lx = tid % 18, ly = tid / 18;
    int gx = tx*18 + lx;
    int gy = ty*14 + ly;
    bool active = (tid < 252) && (gy < HO);

    const float* hb = h_in + (size_t)b * SPIX * 16;

    __shared__ float4 htileV[4][320];   // planar: 16B lane stride, conflict-free
    {
        int gy0 = ty*14 - 1, gx0 = tx*18 - 1;
        for (int i = tid; i < 320; i += 256) {
            int iy = i / 20, ix = i % 20;
            int hy = gy0 + iy, hx = gx0 + ix;
            bool ok = (hy >= 0) & (hy < HO) & (hx >= 0) & (hx < WO);
            const float4* src = (const float4*)(hb + ((size_t)hy * WO + hx) * 16);
            #pragma unroll
            for (int v = 0; v < 4; ++v)
                htileV[v][i] = ok ? src[v] : make_float4(0.f, 0.f, 0.f, 0.f);
        }
    }
    __syncthreads();

    if (!active) return;

    int r = gy * WO + gx;
    size_t pt = (size_t)b * (TT*SPIX) + (size_t)t * SPIX + r;
    int ch0 = cg * 2;

    float z[8];
    #pragma unroll
    for (int c = 0; c < 2; ++c)
        #pragma unroll
        for (int g = 0; g < 4; ++g)
            z[c*4 + g] = __bfloat162float(zx[(size_t)(g*16 + ch0 + c) * NPT + pt]);

    f2 acc[4];
    #pragma unroll
    for (int i = 0; i < 4; ++i) { acc[i].x = 0.f; acc[i].y = 0.f; }

    #pragma unroll 1
    for (int tap = 0; tap < 9; ++tap) {
        int ky = tap / 3;
        int kx = tap - ky * 3;
        int pix = (ly + ky)*20 + (lx + kx);
        float h[16];
        #pragma unroll
        for (int v = 0; v < 4; ++v) {
            float4 t4 = htileV[v][pix];
            h[v*4+0] = t4.x; h[v*4+1] = t4.y; h[v*4+2] = t4.z; h[v*4+3] = t4.w;
        }
        const float* wt = wcg + tap * 128;
        #pragma unroll 1
        for (int hf = 0; hf < 2; ++hf) {
            const f2* wv = (const f2*)(wt + hf * 64);
            #pragma unroll
            for (int u = 0; u < 8; ++u) {
                float hv = h[hf*8 + u];
                acc[0] += hv * wv[u*4 + 0];
                acc[1] += hv * wv[u*4 + 1];
                acc[2] += hv * wv[u*4 + 2];
                acc[3] += hv * wv[u*4 + 3];
            }
        }
    }

    size_t base = ((size_t)(b * SPIX + r)) * 16 + ch0;
    float2 cold = *(float2*)&cst[base];
    float cn[2], hn[2];
    #pragma unroll
    for (int c = 0; c < 2; ++c) {
        float iv = hsig(z[c*4+0] + acc[c*2+0].x + bias[ 0 + ch0 + c]);
        float fv = hsig(z[c*4+1] + acc[c*2+0].y + bias[16 + ch0 + c]);
        float gv = tanhf(z[c*4+2] + acc[c*2+1].x + bias[32 + ch0 + c]);
        float ov = hsig(z[c*4+3] + acc[c*2+1].y + bias[48 + ch0 + c]);
        float cold_c = (c == 0) ? cold.x : cold.y;
        cn[c] = fv * cold_c + iv * gv;
        hn[c] = ov * tanhf(cn[c]);
    }
    *(float2*)&cst[base]   = make_float2(cn[0], cn[1]);
    *(float2*)&h_out[base] = make_float2(hn[0], hn[1]);
}

// Kernel 3: spatial mean over 54x54 -> dense(16->6) -> softmax. One block per b.
__global__ __launch_bounds__(256) void head_kernel(
    const float* __restrict__ h,    // [8,54,54,16]
    const float* __restrict__ dw,   // [16,6]
    const float* __restrict__ db,   // [6]
    float* __restrict__ out)        // [8,6]
{
    int b = blockIdx.x;
    int tid = threadIdx.x;
    const float* hb = h + (size_t)b * SPIX * 16;
    float s = 0.0f;
    for (int i = tid; i < SPIX*16; i += 256) s += hb[i];
    __shared__ float red[256];
    red[tid] = s;
    __syncthreads();
    for (int st = 128; st >= 16; st >>= 1) {
        if (tid < st) red[tid] += red[tid + st];
        __syncthreads();
    }
    __shared__ float logits[8];
    if (tid < NC) {
        float l = db[tid];
        #pragma unroll
        for (int ch = 0; ch < 16; ++ch)
            l += (red[ch] * (1.0f/2916.0f)) * dw[ch*NC + tid];
        logits[tid] = l;
    }
    __syncthreads();
    if (tid < NC) {
        float m = -1e30f;
        for (int k = 0; k < NC; ++k) m = fmaxf(m, logits[k]);
        float e = expf(logits[tid] - m);
        float d = 0.0f;
        for (int k = 0; k < NC; ++k) d += expf(logits[k] - m);
        out[b*NC + tid] = e / d;
    }
}

extern "C" void kernel_launch(void* const* d_in, const int* in_sizes, int n_in,
                              void* d_out, int out_size, void* d_ws, size_t ws_size,
                              hipStream_t stream) {
    const float* x      = (const float*)d_in[0];
    const float* conv_w = (const float*)d_in[1];
    const float* conv_b = (const float*)d_in[2];
    const float* wk     = (const float*)d_in[3];
    const float* wr     = (const float*)d_in[4];
    const float* bias   = (const float*)d_in[5];
    const float* dw     = (const float*)d_in[6];
    const float* db     = (const float*)d_in[7];
    float* out = (float*)d_out;

    float* ws     = (float*)d_ws;
    float* pooled = ws;                                   // 6,422,528 f
    float* hA     = pooled + POOLED_ELEMS;                //   373,248 f
    float* hB     = hA + HSTATE_ELEMS;
    float* cbuf   = hB + HSTATE_ELEMS;
    float* wpack  = cbuf + HSTATE_ELEMS;                  //     9,216 f (wrpack)
    __hip_bfloat16* zx = (__hip_bfloat16*)(wpack + WPACK_ELEMS); // 47.8 MB

    // h0 = 0, c0 = 0 (ws is poisoned before every launch)
    hipMemsetAsync(hA,   0, HSTATE_ELEMS * sizeof(float), stream);
    hipMemsetAsync(cbuf, 0, HSTATE_ELEMS * sizeof(float), stream);

    repack_kernel<<<dim3(36), dim3(256), 0, stream>>>(wr, wpack);
    conv_pool_kernel<<<dim3(14, 128), dim3(256), 0, stream>>>(x, conv_w, conv_b, pooled);
    zx_all_kernel<<<dim3(1458, 2), dim3(256), 0, stream>>>(pooled, wk, zx);

    for (int t = 0; t < TT; ++t) {
        const float* hin  = (t & 1) ? hB : hA;
        float*       hout = (t & 1) ? hA : hB;
        lstm_step_kernel<<<dim3(12, 8, 8), dim3(256), 0, stream>>>(
            zx, hin, hout, cbuf, wpack, bias, t);
    }
    // t=15 (odd) wrote hA
    head_kernel<<<dim3(8), dim3(256), 0, stream>>>(hA, dw, db, out);
}

// Round 15
// 413.922 us; speedup vs baseline: 3.0414x; 1.1096x over previous
//
#include <hip/hip_runtime.h>
#include <hip/hip_bf16.h>
#include <math.h>

// Problem dims
#define BB 8
#define TT 16
#define HH 112
#define WW 112
#define CC 3
#define FF 16
#define HP 56
#define WP 56
#define HO 54
#define WO 54
#define NC 6

#define NPIX (BB*HO*WO)               // 23328
#define SPIX (HO*WO)                  // 2916
#define NPT  (BB*TT*SPIX)             // 373248  (b,t,pixel)

#define HSTATE_ELEMS (BB*SPIX*16)     // 373,248
#define WPACK_ELEMS  9216             // wrpack [8 cg][9 tap][16 ci][2 c][4 g]
#define POOLED_BF16  (128*56*56*16)   // 6,422,528 bf16

typedef __attribute__((ext_vector_type(2))) float f2;
typedef __attribute__((ext_vector_type(8))) short s8v;   // 8 bf16 (4 VGPRs)
typedef __attribute__((ext_vector_type(4))) float f4v;   // MFMA acc

__device__ __forceinline__ float hsig(float x) {
    return fminf(fmaxf(0.2f*x + 0.5f, 0.0f), 1.0f);
}
__device__ __forceinline__ f2 f2max(f2 a, f2 b) {
    f2 r; r.x = fmaxf(a.x, b.x); r.y = fmaxf(a.y, b.y); return r;
}
__device__ __forceinline__ unsigned pk2(float lo, float hi) {
    union { __hip_bfloat16 h; unsigned short u; } a, b;
    a.h = __float2bfloat16(lo); b.h = __float2bfloat16(hi);
    return ((unsigned)b.u << 16) | (unsigned)a.u;
}

// Kernel 0a: repack wr into [cg8][tap][ci][c2][g] (step-kernel consumer).
__global__ __launch_bounds__(256) void repack_kernel(
    const float* __restrict__ wr, float* __restrict__ wpack)
{
    int j = blockIdx.x * 256 + threadIdx.x;        // 36*256 = 9216 exact
    int g   = j & 3;
    int c   = (j >> 2) & 1;
    int ci  = (j >> 3) & 15;
    int tap = (j >> 7) % 9;
    int cg8 = (j >> 7) / 9;
    wpack[j] = wr[tap*1024 + ci*64 + g*16 + cg8*2 + c];
}

// Kernel 0b: prepack wk into MFMA B-fragment order, bf16:
// wkb[nt][ks][lane][j]  (nt=n-tile 0..3, ks=k-step 0..4, 64 lanes, 8 elems)
// B[k][n] with k = ks*32 + (lane>>4)*8 + j (zero for k>=144), n = nt*16+(lane&15).
__global__ __launch_bounds__(256) void wk_prepack_kernel(
    const float* __restrict__ wk, __hip_bfloat16* __restrict__ wkb)
{
    int i = blockIdx.x * 256 + threadIdx.x;        // 40*256 = 10240 exact
    int j    = i & 7;
    int lane = (i >> 3) & 63;
    int ks   = (i >> 9) % 5;
    int nt   = (i >> 9) / 5;
    int k = ks*32 + ((lane >> 4) & 3)*8 + j;
    int n = nt*16 + (lane & 15);
    float v = 0.f;
    if (k < 144) {
        int tap = k >> 4, ci = k & 15;
        v = wk[tap*1024 + ci*64 + n];
    }
    wkb[i] = __float2bfloat16(v);
}

// Kernel 1: fused 7x7 SAME conv (3->16) + bias + relu + 2x2 maxpool.
// R13 body; output now BF16 (only zx_mfma consumes pooled) -> halves writes.
__global__ __launch_bounds__(256, 4) void conv_pool_kernel(
    const float* __restrict__ x,      // [128,112,112,3]
    const float* __restrict__ cw,     // [7,7,3,16]
    const float* __restrict__ cb,     // [16]
    __hip_bfloat16* __restrict__ pooled)  // [128,56,56,16] bf16
{
    int fr = blockIdx.y;
    int tx = blockIdx.x & 1, ty = blockIdx.x >> 1;   // 2 x 7 tiles
    int col0 = tx*28, row0 = ty*8;
    int tid = threadIdx.x;
    const float* xf = x + (size_t)fr * (HH*WW*CC);

    __shared__ float xs[2*22*31*3];
    {
        int ir0 = 2*row0 - 3;
        int ic0 = 2*col0 - 3;
        #pragma unroll 1
        for (int i = tid; i < 22*62*3; i += 256) {
            int iy  = i / 186;
            int rem = i - iy*186;
            int c   = rem / 3;
            int ci  = rem - c*3;
            int gr = ir0 + iy;
            int gc = ic0 + c;
            bool ok = (gr >= 0) & (gr < HH) & (gc >= 0) & (gc < WW);
            float v = ok ? xf[(gr*WW + gc)*3 + ci] : 0.f;
            xs[(c & 1)*2046 + iy*93 + (c >> 1)*3 + ci] = v;
        }
    }
    __syncthreads();

    if (tid >= 224) return;
    int lx = tid % 28, ly = tid / 28;

    const f2* cb2 = (const f2*)cb;
    f2 best[8];
    #pragma unroll
    for (int i = 0; i < 8; ++i) { best[i].x = -1e30f; best[i].y = -1e30f; }

    #pragma unroll 1
    for (int pos = 0; pos < 4; ++pos) {
        int py = pos >> 1, px = pos & 1;
        f2 acc[8];
        #pragma unroll
        for (int i = 0; i < 8; ++i) acc[i] = cb2[i];
        #pragma unroll 1
        for (int ky = 0; ky < 7; ++ky) {
            int row = 2*ly + py + ky;
            const float* rowbase = &xs[row*93 + lx*3];
            #pragma unroll
            for (int kx = 0; kx < 7; ++kx) {
                int s = px + kx;                // px runtime 0/1, kx const
                const float* xp = rowbase + (s & 1)*2046 + (s >> 1)*3;
                const f2* wv = (const f2*)(cw + ((ky*7 + kx)*3)*16);
                #pragma unroll
                for (int ci = 0; ci < 3; ++ci) {
                    float a = xp[ci];
                    #pragma unroll
                    for (int i8 = 0; i8 < 8; ++i8)
                        acc[i8] += a * wv[ci*8 + i8];
                }
            }
        }
        #pragma unroll
        for (int i = 0; i < 8; ++i) best[i] = f2max(best[i], acc[i]);
    }

    int pr = row0 + ly, pc = col0 + lx;
    __hip_bfloat16* op = pooled + (((size_t)fr*HP + pr)*WP + pc)*16;
    unsigned w[8];
    #pragma unroll
    for (int i = 0; i < 8; ++i)
        w[i] = pk2(fmaxf(best[i].x, 0.f), fmaxf(best[i].y, 0.f));
    uint4 u0 = make_uint4(w[0], w[1], w[2], w[3]);
    uint4 u1 = make_uint4(w[4], w[5], w[6], w[7]);
    *(uint4*)op       = u0;
    *(uint4*)(op + 8) = u1;
}

// Kernel 2a: zx via MFMA. zx[n][pt] = sum_k pooled_im2col[pt][k] * wk[k][n],
// K = 9 taps x 16 ci = 144 (padded to 160 = 5 k-steps of 32).
// One wave = one m-tile (16 consecutive pt) x all 4 n-tiles.
// A-frag: lane holds A[m=lane&15][k=(lane>>4)*8+j] -> ONE 16B contiguous load
// from the bf16 NHWC pooled frame (8 consecutive ci of one tap). B prepacked.
// C/D: n=lane&15, m=(lane>>4)*4+reg (m89-verified) -> 8B packed store per nt.
__global__ __launch_bounds__(256, 4) void zx_mfma_kernel(
    const __hip_bfloat16* __restrict__ pooled,  // [128][56][56][16] bf16
    const __hip_bfloat16* __restrict__ wkb,     // [4][5][64][8] bf16
    __hip_bfloat16* __restrict__ zx)            // [64][373248] bf16
{
    int wid  = (blockIdx.x << 2) + (threadIdx.x >> 6);  // m-tile id, 0..23327
    int lane = threadIdx.x & 63;
    int quad = lane >> 4;
    int pt0  = wid << 4;
    int m    = pt0 + (lane & 15);

    // decode pixel m -> frame, oh, ow
    int b  = m / (TT*SPIX);
    int rt = m % (TT*SPIX);
    int tt = rt / SPIX;
    int r  = rt % SPIX;
    int oh = r / WO, ow = r % WO;
    const __hip_bfloat16* pf = pooled + (size_t)(b*TT + tt) * (HP*WP*16);

    f4v acc0 = {0.f,0.f,0.f,0.f}, acc1 = acc0, acc2 = acc0, acc3 = acc0;
    const s8v* wb = (const s8v*)wkb;    // [ (nt*5+ks)*64 + lane ]

    #pragma unroll
    for (int ks = 0; ks < 5; ++ks) {
        int blk = ks*4 + quad;          // k-block of 8, 0..19
        s8v a;
        if (blk < 18) {
            int tap = blk >> 1, half = blk & 1;
            int ky = tap / 3, kx = tap - ky*3;
            a = *(const s8v*)(pf + ((size_t)(oh+ky)*WP + (ow+kx))*16 + half*8);
        } else {
            a = (s8v){0,0,0,0,0,0,0,0};
        }
        acc0 = __builtin_amdgcn_mfma_f32_16x16x32_bf16(a, wb[(0*5+ks)*64 + lane], acc0, 0,0,0);
        acc1 = __builtin_amdgcn_mfma_f32_16x16x32_bf16(a, wb[(1*5+ks)*64 + lane], acc1, 0,0,0);
        acc2 = __builtin_amdgcn_mfma_f32_16x16x32_bf16(a, wb[(2*5+ks)*64 + lane], acc2, 0,0,0);
        acc3 = __builtin_amdgcn_mfma_f32_16x16x32_bf16(a, wb[(3*5+ks)*64 + lane], acc3, 0,0,0);
    }

    // epilogue: lane writes 4 consecutive pt (m = quad*4 + reg) for its n.
    int nlo = lane & 15;
    size_t prow = (size_t)pt0 + quad*4;
    f4v accs[4] = {acc0, acc1, acc2, acc3};
    #pragma unroll
    for (int nt = 0; nt < 4; ++nt) {
        int n = nt*16 + nlo;
        uint2 u;
        u.x = pk2(accs[nt].x, accs[nt].y);
        u.y = pk2(accs[nt].z, accs[nt].w);
        *(uint2*)&zx[(size_t)n * NPT + prow] = u;
    }
}

// Kernel 2b: one ConvLSTM step (R13 exactly: planar LDS h-tile, conflict-free
// b128, 8-way cg split -> 3072 waves, scalar wr weights).
__global__ __launch_bounds__(256, 4) void lstm_step_kernel(
    const __hip_bfloat16* __restrict__ zx,  // [64][373248]
    const float* __restrict__ h_in,         // [8,54,54,16]
    float* __restrict__ h_out,
    float* __restrict__ cst,
    const float* __restrict__ wrpack,       // [cg8][tap][ci][c2][g]
    const float* __restrict__ bias,         // [64]
    int t)
{
    int tileid = blockIdx.x;      // 0..11
    int tx = tileid % 3;
    int ty = tileid / 3;
    int b  = blockIdx.y;
    int cg = blockIdx.z;          // 0..7, channels cg*2, cg*2+1
    const float* wcg = wrpack + cg * 1152;

    int tid = threadIdx.x;
    int lx = tid % 18, ly = tid / 18;
    int gx = tx*18 + lx;
    int gy = ty*14 + ly;
    bool active = (tid < 252) && (gy < HO);

    const float* hb = h_in + (size_t)b * SPIX * 16;

    __shared__ float4 htileV[4][320];   // planar: 16B lane stride, conflict-free
    {
        int gy0 = ty*14 - 1, gx0 = tx*18 - 1;
        for (int i = tid; i < 320; i += 256) {
            int iy = i / 20, ix = i % 20;
            int hy = gy0 + iy, hx = gx0 + ix;
            bool ok = (hy >= 0) & (hy < HO) & (hx >= 0) & (hx < WO);
            const float4* src = (const float4*)(hb + ((size_t)hy * WO + hx) * 16);
            #pragma unroll
            for (int v = 0; v < 4; ++v)
                htileV[v][i] = ok ? src[v] : make_float4(0.f, 0.f, 0.f, 0.f);
        }
    }
    __syncthreads();

    if (!active) return;

    int r = gy * WO + gx;
    size_t pt = (size_t)b * (TT*SPIX) + (size_t)t * SPIX + r;
    int ch0 = cg * 2;

    float z[8];
    #pragma unroll
    for (int c = 0; c < 2; ++c)
        #pragma unroll
        for (int g = 0; g < 4; ++g)
            z[c*4 + g] = __bfloat162float(zx[(size_t)(g*16 + ch0 + c) * NPT + pt]);

    f2 acc[4];
    #pragma unroll
    for (int i = 0; i < 4; ++i) { acc[i].x = 0.f; acc[i].y = 0.f; }

    #pragma unroll 1
    for (int tap = 0; tap < 9; ++tap) {
        int ky = tap / 3;
        int kx = tap - ky * 3;
        int pix = (ly + ky)*20 + (lx + kx);
        float h[16];
        #pragma unroll
        for (int v = 0; v < 4; ++v) {
            float4 t4 = htileV[v][pix];
            h[v*4+0] = t4.x; h[v*4+1] = t4.y; h[v*4+2] = t4.z; h[v*4+3] = t4.w;
        }
        const float* wt = wcg + tap * 128;
        #pragma unroll 1
        for (int hf = 0; hf < 2; ++hf) {
            const f2* wv = (const f2*)(wt + hf * 64);
            #pragma unroll
            for (int u = 0; u < 8; ++u) {
                float hv = h[hf*8 + u];
                acc[0] += hv * wv[u*4 + 0];
                acc[1] += hv * wv[u*4 + 1];
                acc[2] += hv * wv[u*4 + 2];
                acc[3] += hv * wv[u*4 + 3];
            }
        }
    }

    size_t base = ((size_t)(b * SPIX + r)) * 16 + ch0;
    float2 cold = *(float2*)&cst[base];
    float cn[2], hn[2];
    #pragma unroll
    for (int c = 0; c < 2; ++c) {
        float iv = hsig(z[c*4+0] + acc[c*2+0].x + bias[ 0 + ch0 + c]);
        float fv = hsig(z[c*4+1] + acc[c*2+0].y + bias[16 + ch0 + c]);
        float gv = tanhf(z[c*4+2] + acc[c*2+1].x + bias[32 + ch0 + c]);
        float ov = hsig(z[c*4+3] + acc[c*2+1].y + bias[48 + ch0 + c]);
        float cold_c = (c == 0) ? cold.x : cold.y;
        cn[c] = fv * cold_c + iv * gv;
        hn[c] = ov * tanhf(cn[c]);
    }
    *(float2*)&cst[base]   = make_float2(cn[0], cn[1]);
    *(float2*)&h_out[base] = make_float2(hn[0], hn[1]);
}

// Kernel 3: spatial mean over 54x54 -> dense(16->6) -> softmax. One block per b.
__global__ __launch_bounds__(256) void head_kernel(
    const float* __restrict__ h,    // [8,54,54,16]
    const float* __restrict__ dw,   // [16,6]
    const float* __restrict__ db,   // [6]
    float* __restrict__ out)        // [8,6]
{
    int b = blockIdx.x;
    int tid = threadIdx.x;
    const float* hb = h + (size_t)b * SPIX * 16;
    float s = 0.0f;
    for (int i = tid; i < SPIX*16; i += 256) s += hb[i];
    __shared__ float red[256];
    red[tid] = s;
    __syncthreads();
    for (int st = 128; st >= 16; st >>= 1) {
        if (tid < st) red[tid] += red[tid + st];
        __syncthreads();
    }
    __shared__ float logits[8];
    if (tid < NC) {
        float l = db[tid];
        #pragma unroll
        for (int ch = 0; ch < 16; ++ch)
            l += (red[ch] * (1.0f/2916.0f)) * dw[ch*NC + tid];
        logits[tid] = l;
    }
    __syncthreads();
    if (tid < NC) {
        float m = -1e30f;
        for (int k = 0; k < NC; ++k) m = fmaxf(m, logits[k]);
        float e = expf(logits[tid] - m);
        float d = 0.0f;
        for (int k = 0; k < NC; ++k) d += expf(logits[k] - m);
        out[b*NC + tid] = e / d;
    }
}

extern "C" void kernel_launch(void* const* d_in, const int* in_sizes, int n_in,
                              void* d_out, int out_size, void* d_ws, size_t ws_size,
                              hipStream_t stream) {
    const float* x      = (const float*)d_in[0];
    const float* conv_w = (const float*)d_in[1];
    const float* conv_b = (const float*)d_in[2];
    const float* wk     = (const float*)d_in[3];
    const float* wr     = (const float*)d_in[4];
    const float* bias   = (const float*)d_in[5];
    const float* dw     = (const float*)d_in[6];
    const float* db     = (const float*)d_in[7];
    float* out = (float*)d_out;

    char* base = (char*)d_ws;
    __hip_bfloat16* pooled = (__hip_bfloat16*)base;           // 12,845,056 B
    float* hA   = (float*)(base + (size_t)POOLED_BF16 * 2);
    float* hB   = hA + HSTATE_ELEMS;
    float* cbuf = hB + HSTATE_ELEMS;
    float* wpack = cbuf + HSTATE_ELEMS;                       // 9,216 f
    __hip_bfloat16* wkb = (__hip_bfloat16*)(wpack + WPACK_ELEMS);  // 10,240 bf16
    __hip_bfloat16* zx  = wkb + 10240;                        // 47.8 MB

    // h0 = 0, c0 = 0 (ws is poisoned before every launch)
    hipMemsetAsync(hA,   0, HSTATE_ELEMS * sizeof(float), stream);
    hipMemsetAsync(cbuf, 0, HSTATE_ELEMS * sizeof(float), stream);

    repack_kernel<<<dim3(36), dim3(256), 0, stream>>>(wr, wpack);
    wk_prepack_kernel<<<dim3(40), dim3(256), 0, stream>>>(wk, wkb);
    conv_pool_kernel<<<dim3(14, 128), dim3(256), 0, stream>>>(x, conv_w, conv_b, pooled);
    zx_mfma_kernel<<<dim3(5832), dim3(256), 0, stream>>>(pooled, wkb, zx);

    for (int t = 0; t < TT; ++t) {
        const float* hin  = (t & 1) ? hB : hA;
        float*       hout = (t & 1) ? hA : hB;
        lstm_step_kernel<<<dim3(12, 8, 8), dim3(256), 0, stream>>>(
            zx, hin, hout, cbuf, wpack, bias, t);
    }
    // t=15 (odd) wrote hA
    head_kernel<<<dim3(8), dim3(256), 0, stream>>>(hA, dw, db, out);
}

// Round 16
// 341.039 us; speedup vs baseline: 3.6913x; 1.2137x over previous
//
#include <hip/hip_runtime.h>
#include <hip/hip_bf16.h>
#include <math.h>

// Problem dims
#define BB 8
#define TT 16
#define HH 112
#define WW 112
#define CC 3
#define FF 16
#define HP 56
#define WP 56
#define HO 54
#define WO 54
#define NC 6

#define NPIX (BB*HO*WO)               // 23328
#define SPIX (HO*WO)                  // 2916
#define NPT  (BB*TT*SPIX)             // 373248  (b,t,pixel)
#define POOLED_BF16  (128*56*56*16)   // 6,422,528 bf16

typedef __attribute__((ext_vector_type(2))) float f2;
typedef __attribute__((ext_vector_type(8))) short s8v;   // 8 bf16 (4 VGPRs)
typedef __attribute__((ext_vector_type(4))) float f4v;   // MFMA acc

__device__ __forceinline__ float hsig(float x) {
    return fminf(fmaxf(0.2f*x + 0.5f, 0.0f), 1.0f);
}
__device__ __forceinline__ f2 f2max(f2 a, f2 b) {
    f2 r; r.x = fmaxf(a.x, b.x); r.y = fmaxf(a.y, b.y); return r;
}
__device__ __forceinline__ unsigned pk2(float lo, float hi) {
    union { __hip_bfloat16 h; unsigned short u; } a, b;
    a.h = __float2bfloat16(lo); b.h = __float2bfloat16(hi);
    return ((unsigned)b.u << 16) | (unsigned)a.u;
}
__device__ __forceinline__ float bf2f(unsigned short u) {
    union { unsigned v; float f; } x; x.v = ((unsigned)u) << 16; return x.f;
}

// Kernel 0: prepack a [3,3,16,64] weight tensor into MFMA B-fragment order:
// out[nt][ks][lane][j], B[k][n], k = ks*32 + (lane>>4)*8 + j (0 for k>=144),
// n = nt*16 + (lane&15). Used for BOTH wk (zx) and wr (steps).
__global__ __launch_bounds__(256) void w_prepack_kernel(
    const float* __restrict__ w, __hip_bfloat16* __restrict__ wb)
{
    int i = blockIdx.x * 256 + threadIdx.x;        // 40*256 = 10240 exact
    int j    = i & 7;
    int lane = (i >> 3) & 63;
    int ks   = (i >> 9) % 5;
    int nt   = (i >> 9) / 5;
    int k = ks*32 + ((lane >> 4) & 3)*8 + j;
    int n = nt*16 + (lane & 15);
    float v = 0.f;
    if (k < 144) {
        int tap = k >> 4, ci = k & 15;
        v = w[tap*1024 + ci*64 + n];
    }
    wb[i] = __float2bfloat16(v);
}

// Kernel 1: fused 7x7 SAME conv (3->16) + bias + relu + 2x2 maxpool. (R14)
__global__ __launch_bounds__(256, 4) void conv_pool_kernel(
    const float* __restrict__ x,      // [128,112,112,3]
    const float* __restrict__ cw,     // [7,7,3,16]
    const float* __restrict__ cb,     // [16]
    __hip_bfloat16* __restrict__ pooled)  // [128,56,56,16] bf16
{
    int fr = blockIdx.y;
    int tx = blockIdx.x & 1, ty = blockIdx.x >> 1;   // 2 x 7 tiles
    int col0 = tx*28, row0 = ty*8;
    int tid = threadIdx.x;
    const float* xf = x + (size_t)fr * (HH*WW*CC);

    __shared__ float xs[2*22*31*3];
    {
        int ir0 = 2*row0 - 3;
        int ic0 = 2*col0 - 3;
        #pragma unroll 1
        for (int i = tid; i < 22*62*3; i += 256) {
            int iy  = i / 186;
            int rem = i - iy*186;
            int c   = rem / 3;
            int ci  = rem - c*3;
            int gr = ir0 + iy;
            int gc = ic0 + c;
            bool ok = (gr >= 0) & (gr < HH) & (gc >= 0) & (gc < WW);
            float v = ok ? xf[(gr*WW + gc)*3 + ci] : 0.f;
            xs[(c & 1)*2046 + iy*93 + (c >> 1)*3 + ci] = v;
        }
    }
    __syncthreads();

    if (tid >= 224) return;
    int lx = tid % 28, ly = tid / 28;

    const f2* cb2 = (const f2*)cb;
    f2 best[8];
    #pragma unroll
    for (int i = 0; i < 8; ++i) { best[i].x = -1e30f; best[i].y = -1e30f; }

    #pragma unroll 1
    for (int pos = 0; pos < 4; ++pos) {
        int py = pos >> 1, px = pos & 1;
        f2 acc[8];
        #pragma unroll
        for (int i = 0; i < 8; ++i) acc[i] = cb2[i];
        #pragma unroll 1
        for (int ky = 0; ky < 7; ++ky) {
            int row = 2*ly + py + ky;
            const float* rowbase = &xs[row*93 + lx*3];
            #pragma unroll
            for (int kx = 0; kx < 7; ++kx) {
                int s = px + kx;
                const float* xp = rowbase + (s & 1)*2046 + (s >> 1)*3;
                const f2* wv = (const f2*)(cw + ((ky*7 + kx)*3)*16);
                #pragma unroll
                for (int ci = 0; ci < 3; ++ci) {
                    float a = xp[ci];
                    #pragma unroll
                    for (int i8 = 0; i8 < 8; ++i8)
                        acc[i8] += a * wv[ci*8 + i8];
                }
            }
        }
        #pragma unroll
        for (int i = 0; i < 8; ++i) best[i] = f2max(best[i], acc[i]);
    }

    int pr = row0 + ly, pc = col0 + lx;
    __hip_bfloat16* op = pooled + (((size_t)fr*HP + pr)*WP + pc)*16;
    unsigned w[8];
    #pragma unroll
    for (int i = 0; i < 8; ++i)
        w[i] = pk2(fmaxf(best[i].x, 0.f), fmaxf(best[i].y, 0.f));
    *(uint4*)op       = make_uint4(w[0], w[1], w[2], w[3]);
    *(uint4*)(op + 8) = make_uint4(w[4], w[5], w[6], w[7]);
}

// Kernel 2a: zx via MFMA (R14, verified). One wave = 16 pt x 64 gates.
__global__ __launch_bounds__(256, 4) void zx_mfma_kernel(
    const __hip_bfloat16* __restrict__ pooled,  // [128][56][56][16] bf16
    const __hip_bfloat16* __restrict__ wkb,     // [4][5][64][8] bf16
    __hip_bfloat16* __restrict__ zx)            // [64][373248] bf16
{
    int wid  = (blockIdx.x << 2) + (threadIdx.x >> 6);  // 0..23327
    int lane = threadIdx.x & 63;
    int quad = lane >> 4;
    int pt0  = wid << 4;
    int m    = pt0 + (lane & 15);

    int b  = m / (TT*SPIX);
    int rt = m % (TT*SPIX);
    int tt = rt / SPIX;
    int r  = rt % SPIX;
    int oh = r / WO, ow = r % WO;
    const __hip_bfloat16* pf = pooled + (size_t)(b*TT + tt) * (HP*WP*16);

    f4v acc0 = {0.f,0.f,0.f,0.f}, acc1 = acc0, acc2 = acc0, acc3 = acc0;
    const s8v* wb = (const s8v*)wkb;

    #pragma unroll
    for (int ks = 0; ks < 5; ++ks) {
        int blk = ks*4 + quad;          // k-block of 8, 0..19
        s8v a;
        if (blk < 18) {
            int tap = blk >> 1, half = blk & 1;
            int ky = tap / 3, kx = tap - ky*3;
            a = *(const s8v*)(pf + ((size_t)(oh+ky)*WP + (ow+kx))*16 + half*8);
        } else {
            a = (s8v){0,0,0,0,0,0,0,0};
        }
        acc0 = __builtin_amdgcn_mfma_f32_16x16x32_bf16(a, wb[(0*5+ks)*64 + lane], acc0, 0,0,0);
        acc1 = __builtin_amdgcn_mfma_f32_16x16x32_bf16(a, wb[(1*5+ks)*64 + lane], acc1, 0,0,0);
        acc2 = __builtin_amdgcn_mfma_f32_16x16x32_bf16(a, wb[(2*5+ks)*64 + lane], acc2, 0,0,0);
        acc3 = __builtin_amdgcn_mfma_f32_16x16x32_bf16(a, wb[(3*5+ks)*64 + lane], acc3, 0,0,0);
    }

    int nlo = lane & 15;
    size_t prow = (size_t)pt0 + quad*4;
    f4v accs[4] = {acc0, acc1, acc2, acc3};
    #pragma unroll
    for (int nt = 0; nt < 4; ++nt) {
        int n = nt*16 + nlo;
        uint2 u;
        u.x = pk2(accs[nt].x, accs[nt].y);
        u.y = pk2(accs[nt].z, accs[nt].w);
        *(uint2*)&zx[(size_t)n * NPT + prow] = u;
    }
}

// Kernel 2b: one ConvLSTM step via MFMA. Same structure as zx_mfma:
// zh = [23328 px x K=144(h taps,SAME-pad)] . [144 x 64], h stored bf16 NHWC
// so an A k-block (8 ci of one tap) is one guarded 16B load. C/D layout
// (n=lane&15, m=quad*4+reg) means a lane's 4 n-tiles are gates i,f,g,o of
// ONE channel -> gate math is lane-local. c state planar fp32 [16][23328]
// (16B lane loads). 1458 waves, ~20 MFMA/wave.
__global__ __launch_bounds__(256, 4) void lstm_step_mfma(
    const __hip_bfloat16* __restrict__ zx,   // [64][373248]
    const __hip_bfloat16* __restrict__ h_in, // [8,54,54,16] bf16
    __hip_bfloat16* __restrict__ h_out,
    float* __restrict__ cpl,                 // [16][23328] planar fp32
    const __hip_bfloat16* __restrict__ wrb,  // [4][5][64][8] bf16
    const float* __restrict__ bias,          // [64]
    int t)
{
    int wid = (blockIdx.x << 2) + (threadIdx.x >> 6);
    if (wid >= 1458) return;                 // no barriers below
    int lane = threadIdx.x & 63;
    int quad = lane >> 4;
    int pt0  = wid << 4;
    int m    = pt0 + (lane & 15);

    int b  = m / SPIX;
    int r  = m % SPIX;
    int oh = r / WO, ow = r % WO;
    const __hip_bfloat16* hb = h_in + (size_t)b * SPIX * 16;

    f4v acc0 = {0.f,0.f,0.f,0.f}, acc1 = acc0, acc2 = acc0, acc3 = acc0;
    const s8v* wb = (const s8v*)wrb;

    #pragma unroll
    for (int ks = 0; ks < 5; ++ks) {
        int blk = ks*4 + quad;          // k-block of 8, 0..19
        s8v a = (s8v){0,0,0,0,0,0,0,0};
        if (blk < 18) {
            int tap = blk >> 1, half = blk & 1;
            int ky = tap / 3, kx = tap - ky*3;
            int hy = oh + ky - 1, hx = ow + kx - 1;   // SAME pad
            if ((hy >= 0) & (hy < HO) & (hx >= 0) & (hx < WO))
                a = *(const s8v*)(hb + ((size_t)hy*WO + hx)*16 + half*8);
        }
        acc0 = __builtin_amdgcn_mfma_f32_16x16x32_bf16(a, wb[(0*5+ks)*64 + lane], acc0, 0,0,0);
        acc1 = __builtin_amdgcn_mfma_f32_16x16x32_bf16(a, wb[(1*5+ks)*64 + lane], acc1, 0,0,0);
        acc2 = __builtin_amdgcn_mfma_f32_16x16x32_bf16(a, wb[(2*5+ks)*64 + lane], acc2, 0,0,0);
        acc3 = __builtin_amdgcn_mfma_f32_16x16x32_bf16(a, wb[(3*5+ks)*64 + lane], acc3, 0,0,0);
    }

    // Epilogue: lane owns channel ch for pixels pm..pm+3 (one b: 2916%4==0).
    int ch = lane & 15;
    int pm = pt0 + quad*4;
    int b2 = pm / SPIX, r2 = pm % SPIX;
    size_t ptz = (size_t)b2 * (TT*SPIX) + (size_t)t * SPIX + r2;

    ushort4 zi = *(const ushort4*)&zx[(size_t)( 0 + ch) * NPT + ptz];
    ushort4 zf = *(const ushort4*)&zx[(size_t)(16 + ch) * NPT + ptz];
    ushort4 zg = *(const ushort4*)&zx[(size_t)(32 + ch) * NPT + ptz];
    ushort4 zo = *(const ushort4*)&zx[(size_t)(48 + ch) * NPT + ptz];

    float4 cold = *(float4*)&cpl[(size_t)ch * NPIX + pm];
    float b_i = bias[ch], b_f = bias[16+ch], b_g = bias[32+ch], b_o = bias[48+ch];

    float4 cnew;
    unsigned short hn[4];
    float* co = &cold.x; float* cn = &cnew.x;
    const unsigned short* zip = (const unsigned short*)&zi;
    const unsigned short* zfp = (const unsigned short*)&zf;
    const unsigned short* zgp = (const unsigned short*)&zg;
    const unsigned short* zop = (const unsigned short*)&zo;
    float* a0 = (float*)&acc0; float* a1 = (float*)&acc1;
    float* a2 = (float*)&acc2; float* a3 = (float*)&acc3;
    #pragma unroll
    for (int reg = 0; reg < 4; ++reg) {
        float iv = hsig (a0[reg] + bf2f(zip[reg]) + b_i);
        float fv = hsig (a1[reg] + bf2f(zfp[reg]) + b_f);
        float gv = tanhf(a2[reg] + bf2f(zgp[reg]) + b_g);
        float ov = hsig (a3[reg] + bf2f(zop[reg]) + b_o);
        float cc = fv * co[reg] + iv * gv;
        cn[reg] = cc;
        union { __hip_bfloat16 h; unsigned short u; } hv;
        hv.h = __float2bfloat16(ov * tanhf(cc));
        hn[reg] = hv.u;
    }
    *(float4*)&cpl[(size_t)ch * NPIX + pm] = cnew;
    #pragma unroll
    for (int reg = 0; reg < 4; ++reg)
        ((unsigned short*)h_out)[(size_t)(pm + reg) * 16 + ch] = hn[reg];
}

// Kernel 3: spatial mean (bf16 h) -> dense(16->6) -> softmax. One block per b.
__global__ __launch_bounds__(256) void head_kernel(
    const __hip_bfloat16* __restrict__ h,   // [8,54,54,16] bf16
    const float* __restrict__ dw,   // [16,6]
    const float* __restrict__ db,   // [6]
    float* __restrict__ out)        // [8,6]
{
    int b = blockIdx.x;
    int tid = threadIdx.x;
    const __hip_bfloat16* hb = h + (size_t)b * SPIX * 16;
    float s = 0.0f;
    for (int i = tid; i < SPIX*16; i += 256) s += __bfloat162float(hb[i]);
    __shared__ float red[256];
    red[tid] = s;
    __syncthreads();
    for (int st = 128; st >= 16; st >>= 1) {
        if (tid < st) red[tid] += red[tid + st];
        __syncthreads();
    }
    __shared__ float logits[8];
    if (tid < NC) {
        float l = db[tid];
        #pragma unroll
        for (int ch = 0; ch < 16; ++ch)
            l += (red[ch] * (1.0f/2916.0f)) * dw[ch*NC + tid];
        logits[tid] = l;
    }
    __syncthreads();
    if (tid < NC) {
        float m = -1e30f;
        for (int k = 0; k < NC; ++k) m = fmaxf(m, logits[k]);
        float e = expf(logits[tid] - m);
        float d = 0.0f;
        for (int k = 0; k < NC; ++k) d += expf(logits[k] - m);
        out[b*NC + tid] = e / d;
    }
}

extern "C" void kernel_launch(void* const* d_in, const int* in_sizes, int n_in,
                              void* d_out, int out_size, void* d_ws, size_t ws_size,
                              hipStream_t stream) {
    const float* x      = (const float*)d_in[0];
    const float* conv_w = (const float*)d_in[1];
    const float* conv_b = (const float*)d_in[2];
    const float* wk     = (const float*)d_in[3];
    const float* wr     = (const float*)d_in[4];
    const float* bias   = (const float*)d_in[5];
    const float* dw     = (const float*)d_in[6];
    const float* db     = (const float*)d_in[7];
    float* out = (float*)d_out;

    char* base = (char*)d_ws;
    __hip_bfloat16* pooled = (__hip_bfloat16*)base;                 // 12.85 MB
    __hip_bfloat16* hA  = pooled + POOLED_BF16;                     // 746 KB
    __hip_bfloat16* hB  = hA + NPIX*16;
    __hip_bfloat16* wkb = hB + NPIX*16;                             // 20 KB
    __hip_bfloat16* wrb = wkb + 10240;                              // 20 KB
    float* cpl = (float*)(wrb + 10240);                             // 1.49 MB
    __hip_bfloat16* zx  = (__hip_bfloat16*)(cpl + NPIX*16);         // 47.8 MB

    // h0 = 0 (bf16 zero = 0x0000), c0 = 0
    hipMemsetAsync(hA,  0, (size_t)NPIX * 16 * sizeof(__hip_bfloat16), stream);
    hipMemsetAsync(cpl, 0, (size_t)NPIX * 16 * sizeof(float), stream);

    w_prepack_kernel<<<dim3(40), dim3(256), 0, stream>>>(wk, wkb);
    w_prepack_kernel<<<dim3(40), dim3(256), 0, stream>>>(wr, wrb);
    conv_pool_kernel<<<dim3(14, 128), dim3(256), 0, stream>>>(x, conv_w, conv_b, pooled);
    zx_mfma_kernel<<<dim3(5832), dim3(256), 0, stream>>>(pooled, wkb, zx);

    for (int t = 0; t < TT; ++t) {
        const __hip_bfloat16* hin  = (t & 1) ? hB : hA;
        __hip_bfloat16*       hout = (t & 1) ? hA : hB;
        lstm_step_mfma<<<dim3(365), dim3(256), 0, stream>>>(
            zx, hin, hout, cpl, wrb, bias, t);
    }
    // t=15 (odd) wrote hA
    head_kernel<<<dim3(8), dim3(256), 0, stream>>>(hA, dw, db, out);
}

// Round 17
// 326.144 us; speedup vs baseline: 3.8599x; 1.0457x over previous
//
#include <hip/hip_runtime.h>
#include <hip/hip_bf16.h>
#include <math.h>

// Problem dims
#define BB 8
#define TT 16
#define HH 112
#define WW 112
#define CC 3
#define FF 16
#define HP 56
#define WP 56
#define HO 54
#define WO 54
#define NC 6

#define NPIX (BB*HO*WO)               // 23328
#define SPIX (HO*WO)                  // 2916
#define NPT  (BB*TT*SPIX)             // 373248  (b,t,pixel)
#define POOLED_BF16  (128*56*56*16)   // 6,422,528 bf16

// xpad: per-frame bf16 rows with halo + pad: 118 rows x 360 elems
#define XROW 360
#define XFRM (118*XROW)               // 42,480
#define XPAD_ELEMS (128*XFRM)         // 5,437,440 per parity copy

typedef __attribute__((ext_vector_type(8))) short s8v;   // 8 bf16 (4 VGPRs)
typedef __attribute__((ext_vector_type(4))) float f4v;   // MFMA acc

__device__ __forceinline__ float hsig(float x) {
    return fminf(fmaxf(0.2f*x + 0.5f, 0.0f), 1.0f);
}
__device__ __forceinline__ unsigned pk2(float lo, float hi) {
    union { __hip_bfloat16 h; unsigned short u; } a, b;
    a.h = __float2bfloat16(lo); b.h = __float2bfloat16(hi);
    return ((unsigned)b.u << 16) | (unsigned)a.u;
}
__device__ __forceinline__ float bf2f(unsigned short u) {
    union { unsigned v; float f; } x; x.v = ((unsigned)u) << 16; return x.f;
}

// Kernel 0a: prepack a [3,3,16,64] weight tensor into MFMA B-fragment order
// (K=144 pad 160): out[nt][ks][lane][j]. Used for BOTH wk and wr.
__global__ __launch_bounds__(256) void w_prepack_kernel(
    const float* __restrict__ w, __hip_bfloat16* __restrict__ wb)
{
    int i = blockIdx.x * 256 + threadIdx.x;        // 40*256 = 10240 exact
    int j    = i & 7;
    int lane = (i >> 3) & 63;
    int ks   = (i >> 9) % 5;
    int nt   = (i >> 9) / 5;
    int k = ks*32 + ((lane >> 4) & 3)*8 + j;
    int n = nt*16 + (lane & 15);
    float v = 0.f;
    if (k < 144) {
        int tap = k >> 4, ci = k & 15;
        v = w[tap*1024 + ci*64 + n];
    }
    wb[i] = __float2bfloat16(v);
}

// Kernel 0b: prepack conv weights [7,7,3,16] into B-fragment order for the
// conv GEMM: K = 7 rows x 24 (21 real + 3 pad), padded to 192 = 6 k-steps.
// cwb[ks][lane][j]: B[k][n], k = ks*32 + quad*8 + j, n = lane&15.
__global__ __launch_bounds__(256) void cw_prepack_kernel(
    const float* __restrict__ cw, __hip_bfloat16* __restrict__ cwb)
{
    int i = blockIdx.x * 256 + threadIdx.x;        // 12*256 = 3072 exact
    int j    = i & 7;
    int lane = (i >> 3) & 63;
    int ks   = i >> 9;                             // 0..5
    int k = ks*32 + ((lane >> 4) & 3)*8 + j;
    int n = lane & 15;
    float v = 0.f;
    if (k < 168) {
        int row = k / 24, idx = k % 24;
        if (idx < 21) {
            int kx = idx / 3, ci = idx % 3;
            v = cw[((row*7 + kx)*3 + ci)*16 + n];
        }
    }
    cwb[i] = __float2bfloat16(v);
}

// Kernel 0c: build bf16 padded x rows, TWO parity-shifted copies, so every
// A k-block (8 contiguous row elems) is a 4B-aligned 16B load.
// xp_c[fr][rr][e] = val(e - c), val(s) = x[fr][rr-3][(s-9)/3][(s-9)%3]
// for s in [9,345) and rr-3 in [0,112), else 0.
__global__ __launch_bounds__(256) void xpad_kernel(
    const float* __restrict__ x,
    __hip_bfloat16* __restrict__ xp0,
    __hip_bfloat16* __restrict__ xp1)
{
    int idx = blockIdx.x * 256 + threadIdx.x;      // 5310*256 = 1,359,360 exact
    int e4 = idx % 90;
    int rr = (idx / 90) % 118;
    int fr = idx / (90*118);
    int e0 = e4 * 4;
    int ir = rr - 3;
    const float* xf = x + (size_t)fr * (112*336);
    bool rowok = (ir >= 0) & (ir < 112);

    float v[5];
    #pragma unroll
    for (int i = 0; i < 5; ++i) {
        int s = e0 - 1 + i;
        bool ok = rowok & (s >= 9) & (s < 345);
        v[i] = ok ? xf[ir*336 + (s - 9)] : 0.f;
    }
    size_t o = ((size_t)fr*118 + rr) * XROW + e0;
    uint2 a0, a1;
    a0.x = pk2(v[1], v[2]); a0.y = pk2(v[3], v[4]);   // copy0: val(e0..e0+3)
    a1.x = pk2(v[0], v[1]); a1.y = pk2(v[2], v[3]);   // copy1: val(e0-1..e0+2)
    *(uint2*)&xp0[o] = a0;
    *(uint2*)&xp1[o] = a1;
}

// Kernel 1: conv 7x7 (3->16) + bias + relu + 2x2 maxpool, via MFMA.
// GEMM: [1.6M conv px x K=168(pad 192)] . [192 x 16]. One wave = 4 pooled px
// x 4 pool positions (m = local_pooled*4 + pos) x 16 ch. A k-block = one 16B
// contiguous load from the parity-matched xpad copy (4B-aligned). C/D layout
// (m=quad*4+reg) puts the 4 pool positions of one pooled px in one lane's
// regs -> bias+maxpool+relu lane-local. 100,352 waves, 6 MFMA/wave.
__global__ __launch_bounds__(256, 8) void conv_mfma_kernel(
    const __hip_bfloat16* __restrict__ xp0,
    const __hip_bfloat16* __restrict__ xp1,
    const __hip_bfloat16* __restrict__ cwb,  // [6][64][8]
    const float* __restrict__ cb,            // [16]
    __hip_bfloat16* __restrict__ pooled)     // [128,56,56,16] bf16
{
    int w = (blockIdx.x << 2) + (threadIdx.x >> 6);  // wave id 0..100351
    int lane = threadIdx.x & 63;
    int quad = lane >> 4;
    int fr = w / 784;
    int q  = w % 784;
    int p0 = q << 2;                 // pooled px (in-frame) base, 4 per wave
    int m  = lane & 15;
    int pp = p0 + (m >> 2);
    int pos = m & 3;
    int pr = pp / 56, pc = pp % 56;
    int oh = 2*pr + (pos >> 1);      // conv px row 0..111
    int ow = 2*pc + (pos & 1);       // conv px col 0..111

    const __hip_bfloat16* xpc = (ow & 1) ? xp1 : xp0;
    const __hip_bfloat16* xrow = xpc + (size_t)fr*XFRM + ow*3 + (ow & 1);

    f4v acc = {0.f,0.f,0.f,0.f};
    const s8v* wb = (const s8v*)cwb;
    #pragma unroll
    for (int ks = 0; ks < 6; ++ks) {
        int blk = ks*4 + quad;       // k-block of 8, 0..23
        s8v a = (s8v){0,0,0,0,0,0,0,0};
        if (blk < 21) {              // rows 0..6, 3 blocks each
            int row = blk / 3;
            int off = (blk % 3) * 8;
            a = *(const s8v*)(xrow + (size_t)(oh + row)*XROW + off);
        }
        acc = __builtin_amdgcn_mfma_f32_16x16x32_bf16(a, wb[ks*64 + lane], acc, 0,0,0);
    }

    // Epilogue: lane = (pooled px p0+quad, ch nlo); regs = 4 pool positions.
    int nlo = lane & 15;
    float* ap = (float*)&acc;
    float mx = fmaxf(fmaxf(ap[0], ap[1]), fmaxf(ap[2], ap[3]));
    float vv = fmaxf(mx + cb[nlo], 0.f);
    union { __hip_bfloat16 h; unsigned short u; } hv;
    hv.h = __float2bfloat16(vv);
    ((unsigned short*)pooled)[((size_t)fr*3136 + p0 + quad)*16 + nlo] = hv.u;
}

// Kernel 2a: zx via MFMA (R14, verified). One wave = 16 pt x 64 gates.
__global__ __launch_bounds__(256, 4) void zx_mfma_kernel(
    const __hip_bfloat16* __restrict__ pooled,  // [128][56][56][16] bf16
    const __hip_bfloat16* __restrict__ wkb,     // [4][5][64][8] bf16
    __hip_bfloat16* __restrict__ zx)            // [64][373248] bf16
{
    int wid  = (blockIdx.x << 2) + (threadIdx.x >> 6);  // 0..23327
    int lane = threadIdx.x & 63;
    int quad = lane >> 4;
    int pt0  = wid << 4;
    int m    = pt0 + (lane & 15);

    int b  = m / (TT*SPIX);
    int rt = m % (TT*SPIX);
    int tt = rt / SPIX;
    int r  = rt % SPIX;
    int oh = r / WO, ow = r % WO;
    const __hip_bfloat16* pf = pooled + (size_t)(b*TT + tt) * (HP*WP*16);

    f4v acc0 = {0.f,0.f,0.f,0.f}, acc1 = acc0, acc2 = acc0, acc3 = acc0;
    const s8v* wb = (const s8v*)wkb;

    #pragma unroll
    for (int ks = 0; ks < 5; ++ks) {
        int blk = ks*4 + quad;          // k-block of 8, 0..19
        s8v a;
        if (blk < 18) {
            int tap = blk >> 1, half = blk & 1;
            int ky = tap / 3, kx = tap - ky*3;
            a = *(const s8v*)(pf + ((size_t)(oh+ky)*WP + (ow+kx))*16 + half*8);
        } else {
            a = (s8v){0,0,0,0,0,0,0,0};
        }
        acc0 = __builtin_amdgcn_mfma_f32_16x16x32_bf16(a, wb[(0*5+ks)*64 + lane], acc0, 0,0,0);
        acc1 = __builtin_amdgcn_mfma_f32_16x16x32_bf16(a, wb[(1*5+ks)*64 + lane], acc1, 0,0,0);
        acc2 = __builtin_amdgcn_mfma_f32_16x16x32_bf16(a, wb[(2*5+ks)*64 + lane], acc2, 0,0,0);
        acc3 = __builtin_amdgcn_mfma_f32_16x16x32_bf16(a, wb[(3*5+ks)*64 + lane], acc3, 0,0,0);
    }

    int nlo = lane & 15;
    size_t prow = (size_t)pt0 + quad*4;
    f4v accs[4] = {acc0, acc1, acc2, acc3};
    #pragma unroll
    for (int nt = 0; nt < 4; ++nt) {
        int n = nt*16 + nlo;
        uint2 u;
        u.x = pk2(accs[nt].x, accs[nt].y);
        u.y = pk2(accs[nt].z, accs[nt].w);
        *(uint2*)&zx[(size_t)n * NPT + prow] = u;
    }
}

// Kernel 2b: one ConvLSTM step via MFMA (R15, verified).
__global__ __launch_bounds__(256, 4) void lstm_step_mfma(
    const __hip_bfloat16* __restrict__ zx,   // [64][373248]
    const __hip_bfloat16* __restrict__ h_in, // [8,54,54,16] bf16
    __hip_bfloat16* __restrict__ h_out,
    float* __restrict__ cpl,                 // [16][23328] planar fp32
    const __hip_bfloat16* __restrict__ wrb,  // [4][5][64][8] bf16
    const float* __restrict__ bias,          // [64]
    int t)
{
    int wid = (blockIdx.x << 2) + (threadIdx.x >> 6);
    if (wid >= 1458) return;                 // no barriers below
    int lane = threadIdx.x & 63;
    int quad = lane >> 4;
    int pt0  = wid << 4;
    int m    = pt0 + (lane & 15);

    int b  = m / SPIX;
    int r  = m % SPIX;
    int oh = r / WO, ow = r % WO;
    const __hip_bfloat16* hb = h_in + (size_t)b * SPIX * 16;

    f4v acc0 = {0.f,0.f,0.f,0.f}, acc1 = acc0, acc2 = acc0, acc3 = acc0;
    const s8v* wb = (const s8v*)wrb;

    #pragma unroll
    for (int ks = 0; ks < 5; ++ks) {
        int blk = ks*4 + quad;          // k-block of 8, 0..19
        s8v a = (s8v){0,0,0,0,0,0,0,0};
        if (blk < 18) {
            int tap = blk >> 1, half = blk & 1;
            int ky = tap / 3, kx = tap - ky*3;
            int hy = oh + ky - 1, hx = ow + kx - 1;   // SAME pad
            if ((hy >= 0) & (hy < HO) & (hx >= 0) & (hx < WO))
                a = *(const s8v*)(hb + ((size_t)hy*WO + hx)*16 + half*8);
        }
        acc0 = __builtin_amdgcn_mfma_f32_16x16x32_bf16(a, wb[(0*5+ks)*64 + lane], acc0, 0,0,0);
        acc1 = __builtin_amdgcn_mfma_f32_16x16x32_bf16(a, wb[(1*5+ks)*64 + lane], acc1, 0,0,0);
        acc2 = __builtin_amdgcn_mfma_f32_16x16x32_bf16(a, wb[(2*5+ks)*64 + lane], acc2, 0,0,0);
        acc3 = __builtin_amdgcn_mfma_f32_16x16x32_bf16(a, wb[(3*5+ks)*64 + lane], acc3, 0,0,0);
    }

    // Epilogue: lane owns channel ch for pixels pm..pm+3 (one b: 2916%4==0).
    int ch = lane & 15;
    int pm = pt0 + quad*4;
    int b2 = pm / SPIX, r2 = pm % SPIX;
    size_t ptz = (size_t)b2 * (TT*SPIX) + (size_t)t * SPIX + r2;

    ushort4 zi = *(const ushort4*)&zx[(size_t)( 0 + ch) * NPT + ptz];
    ushort4 zf = *(const ushort4*)&zx[(size_t)(16 + ch) * NPT + ptz];
    ushort4 zg = *(const ushort4*)&zx[(size_t)(32 + ch) * NPT + ptz];
    ushort4 zo = *(const ushort4*)&zx[(size_t)(48 + ch) * NPT + ptz];

    float4 cold = *(float4*)&cpl[(size_t)ch * NPIX + pm];
    float b_i = bias[ch], b_f = bias[16+ch], b_g = bias[32+ch], b_o = bias[48+ch];

    float4 cnew;
    unsigned short hn[4];
    float* co = &cold.x; float* cn = &cnew.x;
    const unsigned short* zip = (const unsigned short*)&zi;
    const unsigned short* zfp = (const unsigned short*)&zf;
    const unsigned short* zgp = (const unsigned short*)&zg;
    const unsigned short* zop = (const unsigned short*)&zo;
    float* a0 = (float*)&acc0; float* a1 = (float*)&acc1;
    float* a2 = (float*)&acc2; float* a3 = (float*)&acc3;
    #pragma unroll
    for (int reg = 0; reg < 4; ++reg) {
        float iv = hsig (a0[reg] + bf2f(zip[reg]) + b_i);
        float fv = hsig (a1[reg] + bf2f(zfp[reg]) + b_f);
        float gv = tanhf(a2[reg] + bf2f(zgp[reg]) + b_g);
        float ov = hsig (a3[reg] + bf2f(zop[reg]) + b_o);
        float cc = fv * co[reg] + iv * gv;
        cn[reg] = cc;
        union { __hip_bfloat16 h; unsigned short u; } hv;
        hv.h = __float2bfloat16(ov * tanhf(cc));
        hn[reg] = hv.u;
    }
    *(float4*)&cpl[(size_t)ch * NPIX + pm] = cnew;
    #pragma unroll
    for (int reg = 0; reg < 4; ++reg)
        ((unsigned short*)h_out)[(size_t)(pm + reg) * 16 + ch] = hn[reg];
}

// Kernel 3: spatial mean (bf16 h) -> dense(16->6) -> softmax. One block per b.
__global__ __launch_bounds__(256) void head_kernel(
    const __hip_bfloat16* __restrict__ h,   // [8,54,54,16] bf16
    const float* __restrict__ dw,   // [16,6]
    const float* __restrict__ db,   // [6]
    float* __restrict__ out)        // [8,6]
{
    int b = blockIdx.x;
    int tid = threadIdx.x;
    const __hip_bfloat16* hb = h + (size_t)b * SPIX * 16;
    float s = 0.0f;
    for (int i = tid; i < SPIX*16; i += 256) s += __bfloat162float(hb[i]);
    __shared__ float red[256];
    red[tid] = s;
    __syncthreads();
    for (int st = 128; st >= 16; st >>= 1) {
        if (tid < st) red[tid] += red[tid + st];
        __syncthreads();
    }
    __shared__ float logits[8];
    if (tid < NC) {
        float l = db[tid];
        #pragma unroll
        for (int ch = 0; ch < 16; ++ch)
            l += (red[ch] * (1.0f/2916.0f)) * dw[ch*NC + tid];
        logits[tid] = l;
    }
    __syncthreads();
    if (tid < NC) {
        float m = -1e30f;
        for (int k = 0; k < NC; ++k) m = fmaxf(m, logits[k]);
        float e = expf(logits[tid] - m);
        float d = 0.0f;
        for (int k = 0; k < NC; ++k) d += expf(logits[k] - m);
        out[b*NC + tid] = e / d;
    }
}

extern "C" void kernel_launch(void* const* d_in, const int* in_sizes, int n_in,
                              void* d_out, int out_size, void* d_ws, size_t ws_size,
                              hipStream_t stream) {
    const float* x      = (const float*)d_in[0];
    const float* conv_w = (const float*)d_in[1];
    const float* conv_b = (const float*)d_in[2];
    const float* wk     = (const float*)d_in[3];
    const float* wr     = (const float*)d_in[4];
    const float* bias   = (const float*)d_in[5];
    const float* dw     = (const float*)d_in[6];
    const float* db     = (const float*)d_in[7];
    float* out = (float*)d_out;

    char* base = (char*)d_ws;
    __hip_bfloat16* pooled = (__hip_bfloat16*)base;                 // 12.85 MB
    __hip_bfloat16* hA  = pooled + POOLED_BF16;                     // 746 KB
    __hip_bfloat16* hB  = hA + NPIX*16;
    __hip_bfloat16* wkb = hB + NPIX*16;                             // 20 KB
    __hip_bfloat16* wrb = wkb + 10240;                              // 20 KB
    __hip_bfloat16* cwb = wrb + 10240;                              // 6 KB
    float* cpl = (float*)(cwb + 3072);                              // 1.49 MB
    __hip_bfloat16* zx  = (__hip_bfloat16*)(cpl + NPIX*16);         // 47.8 MB
    // xpad parity copies ALIAS the zx buffer: consumed by conv_mfma BEFORE
    // zx_mfma writes zx (stream-ordered). 2 x 10.9 MB <= 47.8 MB.
    __hip_bfloat16* xp0 = zx;
    __hip_bfloat16* xp1 = zx + XPAD_ELEMS;

    // h0 = 0 (bf16 zero = 0x0000), c0 = 0
    hipMemsetAsync(hA,  0, (size_t)NPIX * 16 * sizeof(__hip_bfloat16), stream);
    hipMemsetAsync(cpl, 0, (size_t)NPIX * 16 * sizeof(float), stream);

    w_prepack_kernel<<<dim3(40), dim3(256), 0, stream>>>(wk, wkb);
    w_prepack_kernel<<<dim3(40), dim3(256), 0, stream>>>(wr, wrb);
    cw_prepack_kernel<<<dim3(12), dim3(256), 0, stream>>>(conv_w, cwb);
    xpad_kernel<<<dim3(5310), dim3(256), 0, stream>>>(x, xp0, xp1);
    conv_mfma_kernel<<<dim3(25088), dim3(256), 0, stream>>>(xp0, xp1, cwb, conv_b, pooled);
    zx_mfma_kernel<<<dim3(5832), dim3(256), 0, stream>>>(pooled, wkb, zx);

    for (int t = 0; t < TT; ++t) {
        const __hip_bfloat16* hin  = (t & 1) ? hB : hA;
        __hip_bfloat16*       hout = (t & 1) ? hA : hB;
        lstm_step_mfma<<<dim3(365), dim3(256), 0, stream>>>(
            zx, hin, hout, cpl, wrb, bias, t);
    }
    // t=15 (odd) wrote hA
    head_kernel<<<dim3(8), dim3(256), 0, stream>>>(hA, dw, db, out);
}